// Round 9
// baseline (233.412 us; speedup 1.0000x reference)
//
#include <hip/hip_runtime.h>
#include <hip/hip_bf16.h>
#include <cstdint>
#include <cstddef>

typedef __hip_bfloat16 bf16;
typedef float  floatx4 __attribute__((ext_vector_type(4)));
typedef __bf16 bf16x8  __attribute__((ext_vector_type(8)));

typedef __attribute__((address_space(1))) void as1_void;
typedef __attribute__((address_space(3))) void as3_void;

constexpr int Bn = 4, Ln = 2048, Cn = 1024;

__device__ __forceinline__ void store_one(float* p, float v) { *p = v; }
__device__ __forceinline__ void store_one(bf16*  p, float v) { *p = __float2bfloat16(v); }

// ---------------------------------------------------------------------------
// LESSONS LEDGER
// R1: T2 swizzle verified (SQ_LDS_BANK_CONFLICT == 0).
// R2: NO intra-kernel cross-block sync (fence+spin = coherence storm, +90us).
// R3: NO bulk fp32 global atomics (16.8M adds ~ +20us tax).
// R4: top dispatches = harness ws re-poison fills (~40us, 82% HBM) — fixed.
// R5/R6: deeper prefetch moved nothing (cover already >= latency).
// R8: 2 blocks/CU alone: 45->43 only. Cycle budget: 128^2 core is near its
//     LDS-TRAFFIC floor (12 ds_read_b128/wave/K-tile for 16 MFMA = 0.75
//     reads/MFMA; slot 3225cy vs 2260cy LDS floor). Lever = LDS economy:
//     per-wave 64x64 (acc 4x4) -> 0.5 reads/MFMA, AND keep 2 blocks/CU.
// R9: single-buffer 128x256 core (48KB LDS, 2 barriers/K-tile, per-tile
//     vmcnt(0) drain covered by co-resident block). Regroup: g1=QK+W2,
//     g2=S, g3=VWT+softmax, g4=PV.
// ---------------------------------------------------------------------------
#define BAR()    asm volatile("s_barrier" ::: "memory")
#define VMCNT0() asm volatile("s_waitcnt vmcnt(0)" ::: "memory")
#define SCHEDB() __builtin_amdgcn_sched_barrier(0)
#define STAGE(gp, off) \
    __builtin_amdgcn_global_load_lds((const as1_void*)(gp), (as3_void*)(smem + (off)), 16, 0, 0)

// ---------------------------------------------------------------------------
// R9 core: 128(M) x 256(N), BK=64, SINGLE-buffer 48KB (A 16KB + B 32KB).
// 8 waves (2M x 4N), per-wave 64x64, acc[4][4] -> 16 ds_read_b128 per 32
// MFMA per K-tile (0.5 reads/MFMA, 1.5x better economy than 128^2 core).
// Per K-tile: stage 6 units -> vmcnt(0) -> BAR -> compute (2 kk sub-steps,
// compiler-scheduled) -> BAR. Drain stall hidden by 2nd co-resident block.
// ---------------------------------------------------------------------------
template <typename OutT>
__device__ __forceinline__ void gemm_sb_m128n256(
    char* __restrict__ smem,
    const bf16* __restrict__ A, const bf16* __restrict__ B, OutT* __restrict__ C,
    int m0, int n0, int kend, int lda, int ldb, int ldc, float cscale)
{
    const int tid  = threadIdx.x;
    const int lane = tid & 63;
    const int quad = lane >> 4;
    const int lr   = lane & 15;
    const int wave = tid >> 6;
    const int wm   = (wave >> 2) * 64;    // 2 waves along M (128 rows)
    const int wn   = (wave & 3) * 64;     // 4 waves along N (256 cols)

    floatx4 acc[4][4];
#pragma unroll
    for (int i = 0; i < 4; ++i)
#pragma unroll
        for (int j = 0; j < 4; ++j) { floatx4 z = {0.f, 0.f, 0.f, 0.f}; acc[i][j] = z; }

    // staging: pre-swizzled global source, linear LDS dest (T2 + m104 rule)
    const int srow = tid >> 3;                    // 0..63 within a unit
    const int sx   = (tid & 7) ^ (srow & 7);      // inverse-swizzled k-slot
    const bf16* gA = A + (size_t)(m0 + srow) * lda + sx * 8;
    const bf16* gB = B + (size_t)(n0 + srow) * ldb + sx * 8;
    const int wuni = __builtin_amdgcn_readfirstlane((tid & 0x1C0) * 16);

    const int aoff = (wm + lr) * 64;              // A row elem offset (rows 0..127)
    const int boff = (wn + lr) * 64;              // B row elem offset (rows 0..255)
    const int s0   = (quad ^ (lr & 7)) * 8;       // kk=0 slot; kk=1 is s0^32

    const int NT = kend >> 6;
    const bf16* As = (const bf16*)smem;
    const bf16* Bs = (const bf16*)(smem + 16384);

    for (int t = 0; t < NT; ++t) {
        const int kn = t << 6;
        // stage tile t (A: 2 units, B: 4 units)
        STAGE(gA + kn,             0 * 8192 + wuni);
        STAGE(gA + kn + 64 * lda,  1 * 8192 + wuni);
        STAGE(gB + kn,             16384 + 0 * 8192 + wuni);
        STAGE(gB + kn + 64  * ldb, 16384 + 1 * 8192 + wuni);
        STAGE(gB + kn + 128 * ldb, 16384 + 2 * 8192 + wuni);
        STAGE(gB + kn + 192 * ldb, 16384 + 3 * 8192 + wuni);
        VMCNT0();
        BAR();
        SCHEDB();
#pragma unroll
        for (int kk = 0; kk < 2; ++kk) {
            const int sk = s0 ^ (kk << 5);
            bf16x8 a[4], b[4];
#pragma unroll
            for (int ii = 0; ii < 4; ++ii)
                a[ii] = *(const bf16x8*)(As + aoff + ii * 1024 + sk);
#pragma unroll
            for (int nn = 0; nn < 4; ++nn)
                b[nn] = *(const bf16x8*)(Bs + boff + nn * 1024 + sk);
            __builtin_amdgcn_s_setprio(1);
#pragma unroll
            for (int ii = 0; ii < 4; ++ii)
#pragma unroll
                for (int nn = 0; nn < 4; ++nn)
                    acc[ii][nn] = __builtin_amdgcn_mfma_f32_16x16x32_bf16(
                        a[ii], b[nn], acc[ii][nn], 0, 0, 0);
            __builtin_amdgcn_s_setprio(0);
        }
        SCHEDB();
        if (t + 1 < NT) BAR();               // protect buffer before restage
    }

    // epilogue: C/D layout col=lane&15, row=quad*4+r (m89-verified)
#pragma unroll
    for (int mi = 0; mi < 4; ++mi) {
        const int row = m0 + wm + mi * 16 + quad * 4;
#pragma unroll
        for (int n = 0; n < 4; ++n) {
            const int col = n0 + wn + n * 16 + lr;
            OutT* cp = C + (size_t)row * ldc + col;
#pragma unroll
            for (int r = 0; r < 4; ++r)
                store_one(cp + (size_t)r * ldc, acc[mi][n][r] * cscale);
        }
    }
}

// ---------------------------------------------------------------------------
// R8 core (kept for g2/g4): 128x128, BK=64, dbuf 64KB, 2 blocks/CU.
// ---------------------------------------------------------------------------
template <typename OutT>
__device__ __forceinline__ void gemm128(
    char* __restrict__ smem,
    const bf16* __restrict__ A, const bf16* __restrict__ B, OutT* __restrict__ C,
    int m0, int n0, int kend, int lda, int ldb, int ldc, float cscale)
{
    const int tid  = threadIdx.x;
    const int lane = tid & 63;
    const int quad = lane >> 4;
    const int lr   = lane & 15;
    const int wave = tid >> 6;
    const int wm   = (wave >> 2) * 64;
    const int wn   = (wave & 3) * 32;

    floatx4 acc[4][2];
#pragma unroll
    for (int i = 0; i < 4; ++i)
#pragma unroll
        for (int j = 0; j < 2; ++j) { floatx4 z = {0.f, 0.f, 0.f, 0.f}; acc[i][j] = z; }

    const int srow = tid >> 3;
    const int sx   = (tid & 7) ^ (srow & 7);
    const bf16* gA = A + (size_t)(m0 + srow) * lda + sx * 8;
    const bf16* gB = B + (size_t)(n0 + srow) * ldb + sx * 8;
    const int wuni = __builtin_amdgcn_readfirstlane((tid & 0x1C0) * 16);

    const int aoff = (wm + lr) * 64;
    const int boff = (wn + lr) * 64;
    const int s0   = (quad ^ (lr & 7)) * 8;

    const int NT  = kend >> 6;
    const int BUF = 32768;

#define STG4(KN, bo) do { \
        STAGE(gA + (KN),            (bo) + 0 * 8192 + wuni); \
        STAGE(gA + (KN) + 64 * lda, (bo) + 1 * 8192 + wuni); \
        STAGE(gB + (KN),            (bo) + 16384 + 0 * 8192 + wuni); \
        STAGE(gB + (KN) + 64 * ldb, (bo) + 16384 + 1 * 8192 + wuni); } while (0)

    STG4(0, 0);
    VMCNT0();
    BAR();

#define LDA2(PH, SK) do { _Pragma("unroll") for (int ii = 0; ii < 2; ++ii) \
        a[ii] = *(const bf16x8*)(As + aoff + ((PH) * 2 + ii) * 1024 + (SK)); } while (0)
#define LDB2(SK) do { _Pragma("unroll") for (int nn = 0; nn < 2; ++nn) \
        b[nn] = *(const bf16x8*)(Bs + boff + nn * 1024 + (SK)); } while (0)
#define MFMA4(PH) do { _Pragma("unroll") for (int ii = 0; ii < 2; ++ii) { \
        _Pragma("unroll") for (int nn = 0; nn < 2; ++nn) \
            acc[(PH) * 2 + ii][nn] = __builtin_amdgcn_mfma_f32_16x16x32_bf16( \
                a[ii], b[nn], acc[(PH) * 2 + ii][nn], 0, 0, 0); } } while (0)

    for (int t = 0; t < NT; ++t) {
        const bf16* As = (const bf16*)(smem + (t & 1) * BUF);
        const bf16* Bs = (const bf16*)(smem + (t & 1) * BUF + 16384);
        const int  wl  = ((t + 1) & 1) * BUF;
        const int  kn  = (t + 1) << 6;
        const bool more = (t + 1 < NT);
        bf16x8 a[2], b[2];

        LDB2(s0);
        LDA2(0, s0);
        if (more) STG4(kn, wl);
        BAR(); SCHEDB();
        __builtin_amdgcn_s_setprio(1);
        MFMA4(0);
        __builtin_amdgcn_s_setprio(0);
        SCHEDB();
        BAR();

        LDA2(1, s0);
        BAR(); SCHEDB();
        __builtin_amdgcn_s_setprio(1);
        MFMA4(1);
        __builtin_amdgcn_s_setprio(0);
        SCHEDB();
        BAR();

        LDB2(s0 ^ 32);
        LDA2(0, s0 ^ 32);
        BAR(); SCHEDB();
        __builtin_amdgcn_s_setprio(1);
        MFMA4(0);
        __builtin_amdgcn_s_setprio(0);
        SCHEDB();
        BAR();

        LDA2(1, s0 ^ 32);
        BAR(); SCHEDB();
        __builtin_amdgcn_s_setprio(1);
        MFMA4(1);
        __builtin_amdgcn_s_setprio(0);
        SCHEDB();
        if (more) VMCNT0();
        BAR();
    }
#undef LDA2
#undef LDB2
#undef MFMA4
#undef STG4

#pragma unroll
    for (int mi = 0; mi < 4; ++mi) {
        const int row = m0 + wm + mi * 16 + quad * 4;
#pragma unroll
        for (int n = 0; n < 2; ++n) {
            const int col = n0 + wn + n * 16 + lr;
            OutT* cp = C + (size_t)row * ldc + col;
#pragma unroll
            for (int r = 0; r < 4; ++r)
                store_one(cp + (size_t)r * ldc, acc[mi][n][r] * cscale);
        }
    }
}

// ---------------------------------------------------------------------------
// g1: blocks [0,512)   -> QK = Xb . Wqkb^T (8192x2048): 64mt x 8nt, 128x256.
//     blocks [512,544) -> W2 = Wo.Wv (1024^2): 8mh x 4nt (backfill tail).
// 2 blocks/CU (48KB LDS). XCD x = i&7 owns mt-octave (A panel L2-local).
// ---------------------------------------------------------------------------
__global__ __launch_bounds__(512, 4)
void g1_qk(const bf16* __restrict__ Xb, const bf16* __restrict__ Wqkb,
           const bf16* __restrict__ Wob, const bf16* __restrict__ WvT,
           bf16* __restrict__ QK, bf16* __restrict__ W2)
{
    __shared__ __align__(16) char smem[49152];
    const int i = blockIdx.x;                    // 544
    if (i < 512) {
        const int x = i & 7;
        const int r = i >> 3;                    // 0..63
        const int mt = x * 8 + (r & 7);          // 0..63
        const int nt = r >> 3;                   // 0..7
        gemm_sb_m128n256<bf16>(smem, Xb, Wqkb, QK, mt * 128, nt * 256, 1024, 1024, 1024, 2048, 1.0f);
    } else {
        const int j = i - 512;                   // 0..31
        gemm_sb_m128n256<bf16>(smem, Wob, WvT, W2, (j >> 2) * 128, (j & 3) * 256, 1024, 1024, 1024, 1024, 1.0f);
    }
}

// ---------------------------------------------------------------------------
// g2: S = (Q.K^T)/32, triangular 128-tiles, 136/batch -> 544 blocks (128^2
// dbuf core, 2/CU). xcd = i&7 = 2b+p pins batch to XCD pair.
// ---------------------------------------------------------------------------
__global__ __launch_bounds__(512, 4)
void g2_s(const bf16* __restrict__ QK, bf16* __restrict__ S)
{
    __shared__ __align__(16) char smem[65536];
    const int i = blockIdx.x;                    // 544
    const int b = (i & 7) >> 1;
    const int p = i & 1;
    const int t = (i >> 3) * 2 + p;              // 0..135
    int ti = (int)((sqrtf(8.f * t + 1.f) - 1.f) * 0.5f);
    while ((ti + 1) * (ti + 2) / 2 <= t) ++ti;
    while (ti * (ti + 1) / 2 > t) --ti;
    const int tj = t - ti * (ti + 1) / 2;        // 0..ti, ti<16
    const bf16* Aq = QK + (size_t)b * Ln * 2048;
    const bf16* Bk = Aq + 1024;
    bf16* Sb = S + (size_t)b * Ln * Ln;
    gemm128<bf16>(smem, Aq, Bk, Sb, ti * 128, tj * 128, 1024, 2048, 2048, Ln, 0.03125f);
}

// ---------------------------------------------------------------------------
// softmax: 32 rows per block (8 waves x 4 rows), strided row = idx + 256*j.
// ---------------------------------------------------------------------------
__device__ __forceinline__ float waveMax(float x) {
#pragma unroll
    for (int o = 32; o > 0; o >>= 1) x = fmaxf(x, __shfl_xor(x, o, 64));
    return x;
}
__device__ __forceinline__ float waveSum(float x) {
#pragma unroll
    for (int o = 32; o > 0; o >>= 1) x += __shfl_xor(x, o, 64);
    return x;
}

__device__ void softmax_rows32(bf16* __restrict__ S, int idx)
{
    const int wave = threadIdx.x >> 6, lane = threadIdx.x & 63;
    for (int it4 = 0; it4 < 4; ++it4) {
        const int row = idx + 256 * (wave * 4 + it4);  // 0..8191 = b*L + q
        const int q = row & (Ln - 1);
        bf16* Srow = S + (size_t)row * Ln;
        const int kmax = ((q >> 7) + 1) << 7;
        const int nv = (kmax + 511) >> 9;              // 1..4 chunks of 512
        float x[4][8];
        float m = -1e30f;
        for (int it = 0; it < nv; ++it) {
            int c0 = it * 512 + lane * 8;
            bf16x8 v = *(const bf16x8*)(Srow + c0);
#pragma unroll
            for (int e = 0; e < 8; ++e) {
                float f = (float)v[e];
                f = (c0 + e <= q) ? f : -1e30f;
                x[it][e] = f;
                m = fmaxf(m, f);
            }
        }
        m = waveMax(m);
        float s = 0.f;
        for (int it = 0; it < nv; ++it)
#pragma unroll
            for (int e = 0; e < 8; ++e) {
                float ex = (x[it][e] > -1e29f) ? __expf(x[it][e] - m) : 0.f;
                x[it][e] = ex;
                s += ex;
            }
        s = waveSum(s);
        const float inv = 1.f / s;
        for (int it = 0; it < nv; ++it) {
            bf16x8 o;
#pragma unroll
            for (int e = 0; e < 8; ++e) o[e] = (__bf16)(x[it][e] * inv);
            *(bf16x8*)(Srow + it * 512 + lane * 8) = o;
        }
    }
}

// ---------------------------------------------------------------------------
// g3: blocks [0,256)   -> VWT = W2 . Xb^T (1024x8192): 8mh x 32nt, 128x256.
//     blocks [256,512) -> causal softmax on S (32 strided rows each).
// Exactly 512 blocks = full 2/CU wave; softmax rides under VWT.
// ---------------------------------------------------------------------------
__global__ __launch_bounds__(512, 4)
void g3_vwt_sm(const bf16* __restrict__ W2, const bf16* __restrict__ Xb,
               bf16* __restrict__ VWT, bf16* __restrict__ S)
{
    __shared__ __align__(16) char smem[49152];
    const int i = blockIdx.x;                    // 512
    if (i < 256) {
        const int x = i & 7;
        const int r = i >> 3;                    // 0..31
        const int nt = x * 4 + (r & 3);          // 0..31
        const int mh = r >> 2;                   // 0..7
        gemm_sb_m128n256<bf16>(smem, W2, Xb, VWT, mh * 128, nt * 256, 1024, 1024, 1024, 8192, 1.0f);
    } else {
        softmax_rows32(S, i - 256);
    }
}

// ---------------------------------------------------------------------------
// g4: out = P . VW (fp32). 512 single 128^2 tiles (4b x 16mh x 8nt), causal
// K=(mh+1)*128, heavy-first + dynamic backfill. xcd = i&7 = 2b+p.
// ---------------------------------------------------------------------------
__global__ __launch_bounds__(512, 4)
void g4_out(const bf16* __restrict__ P, const bf16* __restrict__ VWT,
            float* __restrict__ out)
{
    __shared__ __align__(16) char smem[65536];
    const int i = blockIdx.x;                    // 512
    const int b = (i & 7) >> 1, p = i & 1;
    const int nt = p * 4 + ((i >> 3) & 3);       // 0..7
    const int mh = 15 - (i >> 5);                // 15..0, heavy first

    const bf16* Pp = P + (size_t)b * Ln * Ln;
    const bf16* Bv = VWT + (size_t)b * Ln;
    float* Co = out + (size_t)b * Ln * Cn;
    gemm128<float>(smem, Pp, Bv, Co, mh * 128, nt * 128, (mh + 1) * 128, Ln, 8192, Cn, 1.0f);
}

// ---------------------------------------------------------------------------
// cast_all: blocks [0,11264)      element-wise fp32->bf16 (X, Wqk rows, Wout)
//           blocks [11264,12288)  transpose-cast Wv (1024x1024) -> WvT
// ---------------------------------------------------------------------------
__global__ __launch_bounds__(256)
void cast_all(const float* __restrict__ X, const float* __restrict__ Wqkv,
              const float* __restrict__ Wo,
              bf16* __restrict__ Xb, bf16* __restrict__ Wqkb,
              bf16* __restrict__ Wob, bf16* __restrict__ WvT)
{
    int blk = blockIdx.x;
    if (blk < 11264) {
        int i = blk * 256 + threadIdx.x;
        const float* src; bf16* dst; int off;
        if (i < 2097152)                 { src = X;    dst = Xb;   off = i; }
        else if (i < 2097152 + 524288)   { src = Wqkv; dst = Wqkb; off = i - 2097152; }
        else                             { src = Wo;   dst = Wob;  off = i - 2621440; }
        float4 f = ((const float4*)src)[off];
        bf16 o0 = __float2bfloat16(f.x), o1 = __float2bfloat16(f.y);
        bf16 o2 = __float2bfloat16(f.z), o3 = __float2bfloat16(f.w);
        ushort4 u;
        u.x = *(unsigned short*)&o0; u.y = *(unsigned short*)&o1;
        u.z = *(unsigned short*)&o2; u.w = *(unsigned short*)&o3;
        *(ushort4*)(dst + (size_t)off * 4) = u;
    } else {
        __shared__ float t[32][33];
        int tt = blk - 11264;
        int c0 = (tt & 31) * 32;
        int r0 = (tt >> 5) * 32;
        const float* Wv = Wqkv + 2048 * 1024;
        int xcol = threadIdx.x & 31, y0 = threadIdx.x >> 5;
#pragma unroll
        for (int p = 0; p < 4; ++p) {
            int y = y0 + 8 * p;
            t[y][xcol] = Wv[(size_t)(r0 + y) * 1024 + c0 + xcol];
        }
        __syncthreads();
#pragma unroll
        for (int p = 0; p < 4; ++p) {
            int mloc = y0 + 8 * p;
            WvT[(size_t)(c0 + mloc) * 1024 + r0 + xcol] = __float2bfloat16(t[xcol][mloc]);
        }
    }
}

// ---------------------------------------------------------------------------
extern "C" void kernel_launch(void* const* d_in, const int* in_sizes, int n_in,
                              void* d_out, int out_size, void* d_ws, size_t ws_size,
                              hipStream_t stream)
{
    const float* X    = (const float*)d_in[0];   // (B,L,C)
    const float* Wqkv = (const float*)d_in[1];   // (3C,C)
    const float* Wout = (const float*)d_in[2];   // (C,C)
    float* out = (float*)d_out;                  // (B,L,C) fp32

    char* ws = (char*)d_ws;
    const size_t MiB = 1024ull * 1024ull;
    bf16* Xb   = (bf16*)(ws + 0);                // 16 MiB
    bf16* QK   = (bf16*)(ws + 16 * MiB);         // 32 MiB (q cols 0..1023, k cols 1024..2047)
    bf16* VWT  = (bf16*)(ws + 48 * MiB);         // 16 MiB (1024 x 8192, ld 8192)
    bf16* Sbuf = (bf16*)(ws + 64 * MiB);         // 32 MiB (P in place)
    bf16* Wqkb = (bf16*)(ws + 96 * MiB);         // 4 MiB
    bf16* WvT  = (bf16*)(ws + 100 * MiB);        // 2 MiB
    bf16* Wob  = (bf16*)(ws + 102 * MiB);        // 2 MiB
    bf16* W2   = (bf16*)(ws + 104 * MiB);        // 2 MiB  (total 106 MiB)

    cast_all<<<dim3(12288), 256, 0, stream>>>(X, Wqkv, Wout, Xb, Wqkb, Wob, WvT);

    g1_qk<<<dim3(544), 512, 0, stream>>>(Xb, Wqkb, Wob, WvT, QK, W2);

    g2_s<<<dim3(544), 512, 0, stream>>>(QK, Sbuf);

    g3_vwt_sm<<<dim3(512), 512, 0, stream>>>(W2, Xb, VWT, Sbuf);

    g4_out<<<dim3(512), 512, 0, stream>>>(Sbuf, VWT, out);
}

// Round 10
// 225.943 us; speedup vs baseline: 1.0331x; 1.0331x over previous
//
#include <hip/hip_runtime.h>
#include <hip/hip_bf16.h>
#include <cstdint>
#include <cstddef>

typedef __hip_bfloat16 bf16;
typedef float  floatx4 __attribute__((ext_vector_type(4)));
typedef __bf16 bf16x8  __attribute__((ext_vector_type(8)));

typedef __attribute__((address_space(1))) void as1_void;
typedef __attribute__((address_space(3))) void as3_void;

constexpr int Bn = 4, Ln = 2048, Cn = 1024;

__device__ __forceinline__ void store_one(float* p, float v) { *p = v; }
__device__ __forceinline__ void store_one(bf16*  p, float v) { *p = __float2bfloat16(v); }

// ---------------------------------------------------------------------------
// LESSONS LEDGER
// R1: T2 swizzle verified (SQ_LDS_BANK_CONFLICT == 0).
// R2: NO intra-kernel cross-block sync (fence+spin = coherence storm, +90us).
// R3: NO bulk fp32 global atomics (16.8M adds ~ +20us tax).
// R4: top dispatches = harness ws re-poison fills (~40us, 82% HBM) — fixed.
// R5/R6: deeper prefetch moved nothing (cover already >= latency).
// R8: 2 blocks/CU: 45->43 only (~5%) — co-resident blocks drift into VMEM
//     lockstep (shared HBM issue). Core plateau ~800 TF at K=1024 geometry.
// R9: single-buffer 48KB core REGRESSED g1 43->57.5 (MfmaUtil 24.5%):
//     per-tile stage->vmcnt(0)->compute serialization not covered by the
//     co-resident block. REVERTED to R8 dbuf gemm128 everywhere.
// R10: repack the dispatch graph, not the core: VWT depends only on W2+Xb,
//     so L2={QK,W2} L3={S,VWT} L4={softmax} L5={PV uniform-paired blocks
//     (mh, 15-mh) — R5's robust pairing, no slot-topology assumption}.
// ---------------------------------------------------------------------------
#define BAR()    asm volatile("s_barrier" ::: "memory")
#define VMCNT0() asm volatile("s_waitcnt vmcnt(0)" ::: "memory")
#define SCHEDB() __builtin_amdgcn_sched_barrier(0)
#define STAGE(gp, off) \
    __builtin_amdgcn_global_load_lds((const as1_void*)(gp), (as3_void*)(smem + (off)), 16, 0, 0)

// ---------------------------------------------------------------------------
// R8 core (best measured): 128x128, BK=64, dbuf 64KB, 2 blocks/CU.
// ---------------------------------------------------------------------------
template <typename OutT>
__device__ __forceinline__ void gemm128(
    char* __restrict__ smem,
    const bf16* __restrict__ A, const bf16* __restrict__ B, OutT* __restrict__ C,
    int m0, int n0, int kend, int lda, int ldb, int ldc, float cscale)
{
    const int tid  = threadIdx.x;
    const int lane = tid & 63;
    const int quad = lane >> 4;
    const int lr   = lane & 15;
    const int wave = tid >> 6;
    const int wm   = (wave >> 2) * 64;
    const int wn   = (wave & 3) * 32;

    floatx4 acc[4][2];
#pragma unroll
    for (int i = 0; i < 4; ++i)
#pragma unroll
        for (int j = 0; j < 2; ++j) { floatx4 z = {0.f, 0.f, 0.f, 0.f}; acc[i][j] = z; }

    const int srow = tid >> 3;
    const int sx   = (tid & 7) ^ (srow & 7);
    const bf16* gA = A + (size_t)(m0 + srow) * lda + sx * 8;
    const bf16* gB = B + (size_t)(n0 + srow) * ldb + sx * 8;
    const int wuni = __builtin_amdgcn_readfirstlane((tid & 0x1C0) * 16);

    const int aoff = (wm + lr) * 64;
    const int boff = (wn + lr) * 64;
    const int s0   = (quad ^ (lr & 7)) * 8;

    const int NT  = kend >> 6;
    const int BUF = 32768;

#define STG4(KN, bo) do { \
        STAGE(gA + (KN),            (bo) + 0 * 8192 + wuni); \
        STAGE(gA + (KN) + 64 * lda, (bo) + 1 * 8192 + wuni); \
        STAGE(gB + (KN),            (bo) + 16384 + 0 * 8192 + wuni); \
        STAGE(gB + (KN) + 64 * ldb, (bo) + 16384 + 1 * 8192 + wuni); } while (0)

    STG4(0, 0);
    VMCNT0();
    BAR();

#define LDA2(PH, SK) do { _Pragma("unroll") for (int ii = 0; ii < 2; ++ii) \
        a[ii] = *(const bf16x8*)(As + aoff + ((PH) * 2 + ii) * 1024 + (SK)); } while (0)
#define LDB2(SK) do { _Pragma("unroll") for (int nn = 0; nn < 2; ++nn) \
        b[nn] = *(const bf16x8*)(Bs + boff + nn * 1024 + (SK)); } while (0)
#define MFMA4(PH) do { _Pragma("unroll") for (int ii = 0; ii < 2; ++ii) { \
        _Pragma("unroll") for (int nn = 0; nn < 2; ++nn) \
            acc[(PH) * 2 + ii][nn] = __builtin_amdgcn_mfma_f32_16x16x32_bf16( \
                a[ii], b[nn], acc[(PH) * 2 + ii][nn], 0, 0, 0); } } while (0)

    for (int t = 0; t < NT; ++t) {
        const bf16* As = (const bf16*)(smem + (t & 1) * BUF);
        const bf16* Bs = (const bf16*)(smem + (t & 1) * BUF + 16384);
        const int  wl  = ((t + 1) & 1) * BUF;
        const int  kn  = (t + 1) << 6;
        const bool more = (t + 1 < NT);
        bf16x8 a[2], b[2];

        LDB2(s0);
        LDA2(0, s0);
        if (more) STG4(kn, wl);
        BAR(); SCHEDB();
        __builtin_amdgcn_s_setprio(1);
        MFMA4(0);
        __builtin_amdgcn_s_setprio(0);
        SCHEDB();
        BAR();

        LDA2(1, s0);
        BAR(); SCHEDB();
        __builtin_amdgcn_s_setprio(1);
        MFMA4(1);
        __builtin_amdgcn_s_setprio(0);
        SCHEDB();
        BAR();

        LDB2(s0 ^ 32);
        LDA2(0, s0 ^ 32);
        BAR(); SCHEDB();
        __builtin_amdgcn_s_setprio(1);
        MFMA4(0);
        __builtin_amdgcn_s_setprio(0);
        SCHEDB();
        BAR();

        LDA2(1, s0 ^ 32);
        BAR(); SCHEDB();
        __builtin_amdgcn_s_setprio(1);
        MFMA4(1);
        __builtin_amdgcn_s_setprio(0);
        SCHEDB();
        if (more) VMCNT0();
        BAR();
    }
#undef LDA2
#undef LDB2
#undef MFMA4
#undef STG4

    // epilogue: C/D layout col=lane&15, row=quad*4+r (m89-verified)
#pragma unroll
    for (int mi = 0; mi < 4; ++mi) {
        const int row = m0 + wm + mi * 16 + quad * 4;
#pragma unroll
        for (int n = 0; n < 2; ++n) {
            const int col = n0 + wn + n * 16 + lr;
            OutT* cp = C + (size_t)row * ldc + col;
#pragma unroll
            for (int r = 0; r < 4; ++r)
                store_one(cp + (size_t)r * ldc, acc[mi][n][r] * cscale);
        }
    }
}

// ---------------------------------------------------------------------------
// g1 (L2): blocks [0,1024)    -> QK = Xb . Wqkb^T (64mt x 16nt)
//          blocks [1024,1088) -> W2 = Wo . Wv (8 x 8) — the tail.
// XCD x = i&7 owns an mt-octave (Xb A-panel L2-local).
// ---------------------------------------------------------------------------
__global__ __launch_bounds__(512, 4)
void g1_qk(const bf16* __restrict__ Xb, const bf16* __restrict__ Wqkb,
           const bf16* __restrict__ Wob, const bf16* __restrict__ WvT,
           bf16* __restrict__ QK, bf16* __restrict__ W2)
{
    __shared__ __align__(16) char smem[65536];
    const int i = blockIdx.x;                    // 1088
    if (i < 1024) {
        const int x = i & 7;
        const int r = i >> 3;                    // 0..127
        const int mt = x * 8 + (r & 7);          // 0..63
        const int nt = r >> 3;                   // 0..15
        gemm128<bf16>(smem, Xb, Wqkb, QK, mt * 128, nt * 128, 1024, 1024, 1024, 2048, 1.0f);
    } else {
        const int j = i - 1024;                  // 0..63
        gemm128<bf16>(smem, Wob, WvT, W2, (j >> 3) * 128, (j & 7) * 128, 1024, 1024, 1024, 1024, 1.0f);
    }
}

// ---------------------------------------------------------------------------
// g2 (L3): blocks [0,544)     -> S = (Q.K^T)/32 (triangular, 136/batch)
//          blocks [544,1056)  -> VWT = W2 . Xb^T (8mh x 64nt)
// S and VWT are independent given g1 (S needs QK; VWT needs W2+Xb) — one wall
// instead of two. xcd pinning: S by batch pair (i&7=2b+p), VWT by nt-octave.
// ---------------------------------------------------------------------------
__global__ __launch_bounds__(512, 4)
void g2_sv(const bf16* __restrict__ QK, const bf16* __restrict__ W2,
           const bf16* __restrict__ Xb, bf16* __restrict__ S,
           bf16* __restrict__ VWT)
{
    __shared__ __align__(16) char smem[65536];
    const int i = blockIdx.x;                    // 1056
    if (i < 544) {
        const int b = (i & 7) >> 1;
        const int p = i & 1;
        const int t = (i >> 3) * 2 + p;          // 0..135
        int ti = (int)((sqrtf(8.f * t + 1.f) - 1.f) * 0.5f);
        while ((ti + 1) * (ti + 2) / 2 <= t) ++ti;
        while (ti * (ti + 1) / 2 > t) --ti;
        const int tj = t - ti * (ti + 1) / 2;    // 0..ti, ti<16
        const bf16* Aq = QK + (size_t)b * Ln * 2048;
        const bf16* Bk = Aq + 1024;
        bf16* Sb = S + (size_t)b * Ln * Ln;
        gemm128<bf16>(smem, Aq, Bk, Sb, ti * 128, tj * 128, 1024, 2048, 2048, Ln, 0.03125f);
    } else {
        const int j = i - 544;                   // 0..511
        const int x = j & 7;
        const int r = j >> 3;                    // 0..63
        const int nt = x * 8 + (r & 7);          // 0..63
        const int mh = r >> 3;                   // 0..7
        gemm128<bf16>(smem, W2, Xb, VWT, mh * 128, nt * 128, 1024, 1024, 1024, 8192, 1.0f);
    }
}

// ---------------------------------------------------------------------------
// g3 (L4): causal softmax on S, 256 blocks x 32 strided rows. Mem-bound
// (~34 MB causal traffic), ~8us.
// ---------------------------------------------------------------------------
__device__ __forceinline__ float waveMax(float x) {
#pragma unroll
    for (int o = 32; o > 0; o >>= 1) x = fmaxf(x, __shfl_xor(x, o, 64));
    return x;
}
__device__ __forceinline__ float waveSum(float x) {
#pragma unroll
    for (int o = 32; o > 0; o >>= 1) x += __shfl_xor(x, o, 64);
    return x;
}

__global__ __launch_bounds__(512)
void g3_sm(bf16* __restrict__ S)
{
    const int idx = blockIdx.x;                  // 256
    const int wave = threadIdx.x >> 6, lane = threadIdx.x & 63;
    for (int it4 = 0; it4 < 4; ++it4) {
        const int row = idx + 256 * (wave * 4 + it4);  // 0..8191 = b*L + q
        const int q = row & (Ln - 1);
        bf16* Srow = S + (size_t)row * Ln;
        const int kmax = ((q >> 7) + 1) << 7;
        const int nv = (kmax + 511) >> 9;              // 1..4 chunks of 512
        float x[4][8];
        float m = -1e30f;
        for (int it = 0; it < nv; ++it) {
            int c0 = it * 512 + lane * 8;
            bf16x8 v = *(const bf16x8*)(Srow + c0);
#pragma unroll
            for (int e = 0; e < 8; ++e) {
                float f = (float)v[e];
                f = (c0 + e <= q) ? f : -1e30f;
                x[it][e] = f;
                m = fmaxf(m, f);
            }
        }
        m = waveMax(m);
        float s = 0.f;
        for (int it = 0; it < nv; ++it)
#pragma unroll
            for (int e = 0; e < 8; ++e) {
                float ex = (x[it][e] > -1e29f) ? __expf(x[it][e] - m) : 0.f;
                x[it][e] = ex;
                s += ex;
            }
        s = waveSum(s);
        const float inv = 1.f / s;
        for (int it = 0; it < nv; ++it) {
            bf16x8 o;
#pragma unroll
            for (int e = 0; e < 8; ++e) o[e] = (__bf16)(x[it][e] * inv);
            *(bf16x8*)(Srow + it * 512 + lane * 8) = o;
        }
    }
}

// ---------------------------------------------------------------------------
// g4 (L5): out = P . VW (fp32). 256 blocks, each a UNIFORM PAIR of tiles
// (mh=15-h then mh=h) at the same (b,nt): total K = 17*128 = 2176 per block
// regardless of h — balanced with no slot-topology assumption (R5 pattern on
// the proven dbuf core). xcd = i&7 = 2b+p pins batch to XCD pair.
// ---------------------------------------------------------------------------
__global__ __launch_bounds__(512, 4)
void g4_out(const bf16* __restrict__ P, const bf16* __restrict__ VWT,
            float* __restrict__ out)
{
    __shared__ __align__(16) char smem[65536];
    const int i = blockIdx.x;                    // 256
    const int b = (i & 7) >> 1, p = i & 1;
    const int nt = p * 4 + ((i >> 3) & 3);       // 0..7
    const int h = i >> 5;                        // 0..7

    const bf16* Pp = P + (size_t)b * Ln * Ln;
    const bf16* Bv = VWT + (size_t)b * Ln;
    float* Co = out + (size_t)b * Ln * Cn;
    const int n0 = nt * 128;

    // heavy tile first, complementary light tile second (const total work)
    gemm128<float>(smem, Pp, Bv, Co, (15 - h) * 128, n0, (16 - h) * 128, Ln, 8192, Cn, 1.0f);
    gemm128<float>(smem, Pp, Bv, Co, h * 128,        n0, (h + 1) * 128,  Ln, 8192, Cn, 1.0f);
}

// ---------------------------------------------------------------------------
// cast_all: blocks [0,11264)      element-wise fp32->bf16 (X, Wqk rows, Wout)
//           blocks [11264,12288)  transpose-cast Wv (1024x1024) -> WvT
// ---------------------------------------------------------------------------
__global__ __launch_bounds__(256)
void cast_all(const float* __restrict__ X, const float* __restrict__ Wqkv,
              const float* __restrict__ Wo,
              bf16* __restrict__ Xb, bf16* __restrict__ Wqkb,
              bf16* __restrict__ Wob, bf16* __restrict__ WvT)
{
    int blk = blockIdx.x;
    if (blk < 11264) {
        int i = blk * 256 + threadIdx.x;
        const float* src; bf16* dst; int off;
        if (i < 2097152)                 { src = X;    dst = Xb;   off = i; }
        else if (i < 2097152 + 524288)   { src = Wqkv; dst = Wqkb; off = i - 2097152; }
        else                             { src = Wo;   dst = Wob;  off = i - 2621440; }
        float4 f = ((const float4*)src)[off];
        bf16 o0 = __float2bfloat16(f.x), o1 = __float2bfloat16(f.y);
        bf16 o2 = __float2bfloat16(f.z), o3 = __float2bfloat16(f.w);
        ushort4 u;
        u.x = *(unsigned short*)&o0; u.y = *(unsigned short*)&o1;
        u.z = *(unsigned short*)&o2; u.w = *(unsigned short*)&o3;
        *(ushort4*)(dst + (size_t)off * 4) = u;
    } else {
        __shared__ float t[32][33];
        int tt = blk - 11264;
        int c0 = (tt & 31) * 32;
        int r0 = (tt >> 5) * 32;
        const float* Wv = Wqkv + 2048 * 1024;
        int xcol = threadIdx.x & 31, y0 = threadIdx.x >> 5;
#pragma unroll
        for (int p = 0; p < 4; ++p) {
            int y = y0 + 8 * p;
            t[y][xcol] = Wv[(size_t)(r0 + y) * 1024 + c0 + xcol];
        }
        __syncthreads();
#pragma unroll
        for (int p = 0; p < 4; ++p) {
            int mloc = y0 + 8 * p;
            WvT[(size_t)(c0 + mloc) * 1024 + r0 + xcol] = __float2bfloat16(t[xcol][mloc]);
        }
    }
}

// ---------------------------------------------------------------------------
extern "C" void kernel_launch(void* const* d_in, const int* in_sizes, int n_in,
                              void* d_out, int out_size, void* d_ws, size_t ws_size,
                              hipStream_t stream)
{
    const float* X    = (const float*)d_in[0];   // (B,L,C)
    const float* Wqkv = (const float*)d_in[1];   // (3C,C)
    const float* Wout = (const float*)d_in[2];   // (C,C)
    float* out = (float*)d_out;                  // (B,L,C) fp32

    char* ws = (char*)d_ws;
    const size_t MiB = 1024ull * 1024ull;
    bf16* Xb   = (bf16*)(ws + 0);                // 16 MiB
    bf16* QK   = (bf16*)(ws + 16 * MiB);         // 32 MiB (q cols 0..1023, k cols 1024..2047)
    bf16* VWT  = (bf16*)(ws + 48 * MiB);         // 16 MiB (1024 x 8192, ld 8192)
    bf16* Sbuf = (bf16*)(ws + 64 * MiB);         // 32 MiB (P in place)
    bf16* Wqkb = (bf16*)(ws + 96 * MiB);         // 4 MiB
    bf16* WvT  = (bf16*)(ws + 100 * MiB);        // 2 MiB
    bf16* Wob  = (bf16*)(ws + 102 * MiB);        // 2 MiB
    bf16* W2   = (bf16*)(ws + 104 * MiB);        // 2 MiB  (total 106 MiB)

    cast_all<<<dim3(12288), 256, 0, stream>>>(X, Wqkv, Wout, Xb, Wqkb, Wob, WvT);

    g1_qk<<<dim3(1088), 512, 0, stream>>>(Xb, Wqkb, Wob, WvT, QK, W2);

    g2_sv<<<dim3(1056), 512, 0, stream>>>(QK, W2, Xb, Sbuf, VWT);

    g3_sm<<<dim3(256), 512, 0, stream>>>(Sbuf);

    g4_out<<<dim3(256), 512, 0, stream>>>(Sbuf, VWT, out);
}